// Round 4
// baseline (483.794 us; speedup 1.0000x reference)
//
#include <hip/hip_runtime.h>
#include <hip/hip_bf16.h>

typedef float  f32x4 __attribute__((ext_vector_type(4)));
typedef short  s16x8 __attribute__((ext_vector_type(8)));

#define NB   1024
#define SEQ  64
#define DIM  512
#define NH   8
#define SCALE 0.044194173824159216f

// round-half-up f32->bf16: 2 VALU ops
static __device__ __forceinline__ unsigned short f2bf(float f) {
    unsigned u = __builtin_bit_cast(unsigned, f);
    return (unsigned short)((u + 0x8000u) >> 16);
}

static __device__ __forceinline__ f32x4 mma(s16x8 a, s16x8 b, f32x4 c) {
    return __builtin_amdgcn_mfma_f32_16x16x32_bf16(a, b, c, 0, 0, 0);
}

// load 8 consecutive f32, convert to a bf16 frag slice (fallback path only)
static __device__ __forceinline__ s16x8 ldcvt(const float* p) {
    float4 v0 = *(const float4*)(p);
    float4 v1 = *(const float4*)(p + 4);
    s16x8 r;
    r[0] = (short)f2bf(v0.x); r[1] = (short)f2bf(v0.y);
    r[2] = (short)f2bf(v0.z); r[3] = (short)f2bf(v0.w);
    r[4] = (short)f2bf(v1.x); r[5] = (short)f2bf(v1.y);
    r[6] = (short)f2bf(v1.z); r[7] = (short)f2bf(v1.w);
    return r;
}

// Pre-kernel: convert Wq, Wc (f32 [512][512] row-major, [k][n]) into bf16
// B-fragment order: m in {0,1}, tile 0..31, ks 0..15, lane 0..63:
// 8 bf16 = W[ks*32 + (lane>>4)*8 + j][tile*16 + (lane&15)].
__global__ __launch_bounds__(256) void prep_weights(
    const float* __restrict__ Wq, const float* __restrict__ Wc,
    unsigned short* __restrict__ wf)
{
    int gid  = blockIdx.x * 256 + threadIdx.x;   // 0..65535
    int m    = gid >> 15;
    int tile = (gid >> 10) & 31;
    int ks   = (gid >> 6) & 15;
    int lane = gid & 63;
    const float* W = m ? Wc : Wq;
    int col = tile * 16 + (lane & 15);
    int k0  = ks * 32 + (lane >> 4) * 8;
    unsigned short* dst = wf + (size_t)gid * 8;
#pragma unroll
    for (int j = 0; j < 8; ++j)
        dst[j] = f2bf(W[(size_t)(k0 + j) * DIM + col]);
}

// Pre-kernel: f32 -> bf16 activation copy (row-major layout preserved).
// 8 elems/thread: 32B read, 16B write — pure HBM-bound.
__global__ __launch_bounds__(256) void prep_acts(
    const float* __restrict__ src, unsigned short* __restrict__ dst)
{
    size_t i = ((size_t)blockIdx.x * 256 + threadIdx.x) * 8;
    float4 v0 = *(const float4*)(src + i);
    float4 v1 = *(const float4*)(src + i + 4);
    s16x8 r;
    r[0] = (short)f2bf(v0.x); r[1] = (short)f2bf(v0.y);
    r[2] = (short)f2bf(v0.z); r[3] = (short)f2bf(v0.w);
    r[4] = (short)f2bf(v1.x); r[5] = (short)f2bf(v1.y);
    r[6] = (short)f2bf(v1.z); r[7] = (short)f2bf(v1.w);
    *(s16x8*)(dst + i) = r;
}

// One block = (b, half); 4 waves, each wave owns one head. NO barriers.
// PRE=true: activations already bf16 in ws (zero conversion VALU in hot loop).
// PRE=false: fallback converting f32 acts in-kernel (ws too small).
template<bool PRE>
__global__ __launch_bounds__(256) void coattn(
    const float* __restrict__ query,
    const float* __restrict__ context,
    const unsigned short* __restrict__ aq_all,
    const unsigned short* __restrict__ ac_all,
    const float* __restrict__ bq,
    const float* __restrict__ bc,
    const unsigned short* __restrict__ wf,
    float* __restrict__ out)
{
    __shared__ unsigned short sT[4][SEQ][72];   // per-wave 64x64 bf16 tile, padded

    const int tid  = threadIdx.x;
    const int lane = tid & 63;
    const int wv   = tid >> 6;
    const int l15  = lane & 15;
    const int l4   = lane >> 4;

    // chunked swizzle: dispatch round-robins XCDs; ids i and i+8 share an XCD,
    // so make them the two halves of the same b for L2 reuse of activations.
    const int B_id = blockIdx.x;
    const int half = (B_id >> 3) & 1;
    const int b    = (B_id & 7) | ((B_id >> 4) << 3);
    const int h    = half * 4 + wv;

    const float* gq = query   + (size_t)b * SEQ * DIM;
    const float* gc = context + (size_t)b * SEQ * DIM;
    const unsigned short* aq = aq_all + (size_t)b * SEQ * DIM;
    const unsigned short* ac = ac_all + (size_t)b * SEQ * DIM;

    const f32x4 fz = {0.f, 0.f, 0.f, 0.f};
    unsigned short (*T)[72] = sT[wv];

    f32x4 acc[4][4];

    // ================= C projection =================
#pragma unroll
    for (int i = 0; i < 4; ++i)
#pragma unroll
        for (int j = 0; j < 4; ++j) acc[i][j] = fz;

    for (int ks = 0; ks < 16; ++ks) {
        const int k0 = ks * 32 + l4 * 8;
        s16x8 af[4], bf[4];
#pragma unroll
        for (int mt = 0; mt < 4; ++mt) {
            if constexpr (PRE)
                af[mt] = *(const s16x8*)(ac + (size_t)(mt * 16 + l15) * DIM + k0);
            else
                af[mt] = ldcvt(gc + (size_t)(mt * 16 + l15) * DIM + k0);
        }
#pragma unroll
        for (int nt = 0; nt < 4; ++nt)
            bf[nt] = *(const s16x8*)(wf + 262144 +
                     ((size_t)((h * 4 + nt) * 16 + ks) * 64 + lane) * 8);
#pragma unroll
        for (int mt = 0; mt < 4; ++mt)
#pragma unroll
            for (int nt = 0; nt < 4; ++nt)
                acc[mt][nt] = mma(af[mt], bf[nt], acc[mt][nt]);
    }

    // bias + write Cp -> T (C/D layout: row=(l4)*4+r, col=l15)
#pragma unroll
    for (int nt = 0; nt < 4; ++nt) {
        float bcv = bc[h * 64 + nt * 16 + l15];
#pragma unroll
        for (int mt = 0; mt < 4; ++mt)
#pragma unroll
            for (int r = 0; r < 4; ++r)
                T[mt * 16 + l4 * 4 + r][nt * 16 + l15] = f2bf(acc[mt][nt][r] + bcv);
    }

    // Cp^T B-frags (contiguous rows serve Cp^T; n=key, kk=feature)
    s16x8 cb[4][2];
#pragma unroll
    for (int nt = 0; nt < 4; ++nt)
#pragma unroll
        for (int ks = 0; ks < 2; ++ks)
            cb[nt][ks] = *(const s16x8*)&T[nt * 16 + l15][ks * 32 + l4 * 8];

    // ================= Q projection (reuses acc regs) =================
#pragma unroll
    for (int i = 0; i < 4; ++i)
#pragma unroll
        for (int j = 0; j < 4; ++j) acc[i][j] = fz;

    for (int ks = 0; ks < 16; ++ks) {
        const int k0 = ks * 32 + l4 * 8;
        s16x8 af[4], bf[4];
#pragma unroll
        for (int mt = 0; mt < 4; ++mt) {
            if constexpr (PRE)
                af[mt] = *(const s16x8*)(aq + (size_t)(mt * 16 + l15) * DIM + k0);
            else
                af[mt] = ldcvt(gq + (size_t)(mt * 16 + l15) * DIM + k0);
        }
#pragma unroll
        for (int nt = 0; nt < 4; ++nt)
            bf[nt] = *(const s16x8*)(wf +
                     ((size_t)((h * 4 + nt) * 16 + ks) * 64 + lane) * 8);
#pragma unroll
        for (int mt = 0; mt < 4; ++mt)
#pragma unroll
            for (int nt = 0; nt < 4; ++nt)
                acc[mt][nt] = mma(af[mt], bf[nt], acc[mt][nt]);
    }

    // bias + write Qp -> T (overwrites Cp; cb already in regs)
#pragma unroll
    for (int nt = 0; nt < 4; ++nt) {
        float bqv = bq[h * 64 + nt * 16 + l15];
#pragma unroll
        for (int mt = 0; mt < 4; ++mt)
#pragma unroll
            for (int r = 0; r < 4; ++r)
                T[mt * 16 + l4 * 4 + r][nt * 16 + l15] = f2bf(acc[mt][nt][r] + bqv);
    }

    // Qp A-frags (contig) and Qp B-frags (strided transpose reads)
    s16x8 qa[4][2], qb[4][2];
#pragma unroll
    for (int mt = 0; mt < 4; ++mt)
#pragma unroll
        for (int ks = 0; ks < 2; ++ks)
            qa[mt][ks] = *(const s16x8*)&T[mt * 16 + l15][ks * 32 + l4 * 8];
#pragma unroll
    for (int nt = 0; nt < 4; ++nt)
#pragma unroll
        for (int ks = 0; ks < 2; ++ks) {
            s16x8 v;
#pragma unroll
            for (int j = 0; j < 8; ++j)
                v[j] = (short)T[ks * 32 + l4 * 8 + j][nt * 16 + l15];
            qb[nt][ks] = v;
        }

    // ===== attn = Qp @ Cp^T (raw logits; SCALE folded into softmax) =====
    f32x4 Sc[4][4];
#pragma unroll
    for (int i = 0; i < 4; ++i)
#pragma unroll
        for (int j = 0; j < 4; ++j) Sc[i][j] = fz;
#pragma unroll
    for (int ks = 0; ks < 2; ++ks)
#pragma unroll
        for (int mt = 0; mt < 4; ++mt)
#pragma unroll
            for (int nt = 0; nt < 4; ++nt)
                Sc[mt][nt] = mma(qa[mt][ks], cb[nt][ks], Sc[mt][nt]);

    // ===== softmax over k (rows): P1 -> T =====
#pragma unroll
    for (int mt = 0; mt < 4; ++mt)
#pragma unroll
        for (int r = 0; r < 4; ++r) {
            float m = fmaxf(fmaxf(Sc[mt][0][r], Sc[mt][1][r]),
                            fmaxf(Sc[mt][2][r], Sc[mt][3][r]));
            m = fmaxf(m, __shfl_xor(m, 1));
            m = fmaxf(m, __shfl_xor(m, 2));
            m = fmaxf(m, __shfl_xor(m, 4));
            m = fmaxf(m, __shfl_xor(m, 8));
            float e[4], s = 0.f;
#pragma unroll
            for (int nt = 0; nt < 4; ++nt) { e[nt] = __expf(SCALE * (Sc[mt][nt][r] - m)); s += e[nt]; }
            s += __shfl_xor(s, 1);
            s += __shfl_xor(s, 2);
            s += __shfl_xor(s, 4);
            s += __shfl_xor(s, 8);
            float inv = 1.f / s;
            int row = mt * 16 + l4 * 4 + r;
#pragma unroll
            for (int nt = 0; nt < 4; ++nt)
                T[row][nt * 16 + l15] = f2bf(e[nt] * inv);
        }

    s16x8 pa[4][2];
#pragma unroll
    for (int mt = 0; mt < 4; ++mt)
#pragma unroll
        for (int ks = 0; ks < 2; ++ks)
            pa[mt][ks] = *(const s16x8*)&T[mt * 16 + l15][ks * 32 + l4 * 8];

    // ===== softmax over q (cols): P2^T -> T =====
#pragma unroll
    for (int nt = 0; nt < 4; ++nt) {
        float m = -1e30f;
#pragma unroll
        for (int mt = 0; mt < 4; ++mt)
#pragma unroll
            for (int r = 0; r < 4; ++r) m = fmaxf(m, Sc[mt][nt][r]);
        m = fmaxf(m, __shfl_xor(m, 16));
        m = fmaxf(m, __shfl_xor(m, 32));
        float ee[4][4], s = 0.f;
#pragma unroll
        for (int mt = 0; mt < 4; ++mt)
#pragma unroll
            for (int r = 0; r < 4; ++r) { ee[mt][r] = __expf(SCALE * (Sc[mt][nt][r] - m)); s += ee[mt][r]; }
        s += __shfl_xor(s, 16);
        s += __shfl_xor(s, 32);
        float inv = 1.f / s;
        int krow = nt * 16 + l15;
#pragma unroll
        for (int mt = 0; mt < 4; ++mt)
#pragma unroll
            for (int r = 0; r < 4; ++r)
                T[krow][mt * 16 + l4 * 4 + r] = f2bf(ee[mt][r] * inv);
    }

    s16x8 p2a[4][2];
#pragma unroll
    for (int mt = 0; mt < 4; ++mt)
#pragma unroll
        for (int ks = 0; ks < 2; ++ks)
            p2a[mt][ks] = *(const s16x8*)&T[mt * 16 + l15][ks * 32 + l4 * 8];

    // ===== c_coattn = P1 @ Cp^T ; store =====
    f32x4 O[4][4];
#pragma unroll
    for (int i = 0; i < 4; ++i)
#pragma unroll
        for (int j = 0; j < 4; ++j) O[i][j] = fz;
#pragma unroll
    for (int ks = 0; ks < 2; ++ks)
#pragma unroll
        for (int mt = 0; mt < 4; ++mt)
#pragma unroll
            for (int nt = 0; nt < 4; ++nt)
                O[mt][nt] = mma(pa[mt][ks], cb[nt][ks], O[mt][nt]);

    float* cO = out;
#pragma unroll
    for (int mt = 0; mt < 4; ++mt)
#pragma unroll
        for (int nt = 0; nt < 4; ++nt)
#pragma unroll
            for (int r = 0; r < 4; ++r) {
                int qrow = mt * 16 + l4 * 4 + r;
                cO[((size_t)b * SEQ + qrow) * (NH * 64) + h * 64 + nt * 16 + l15] = O[mt][nt][r];
            }

    // ===== q_coattn = P2^T @ Qp ; store =====
#pragma unroll
    for (int i = 0; i < 4; ++i)
#pragma unroll
        for (int j = 0; j < 4; ++j) O[i][j] = fz;
#pragma unroll
    for (int ks = 0; ks < 2; ++ks)
#pragma unroll
        for (int mt = 0; mt < 4; ++mt)
#pragma unroll
            for (int nt = 0; nt < 4; ++nt)
                O[mt][nt] = mma(p2a[mt][ks], qb[nt][ks], O[mt][nt]);

    float* qO = out + (size_t)NB * SEQ * NH * 64;
#pragma unroll
    for (int mt = 0; mt < 4; ++mt)
#pragma unroll
        for (int nt = 0; nt < 4; ++nt)
#pragma unroll
            for (int r = 0; r < 4; ++r) {
                int krow = mt * 16 + l4 * 4 + r;
                qO[((size_t)b * SEQ + krow) * (NH * 64) + h * 64 + nt * 16 + l15] = O[mt][nt][r];
            }
}

extern "C" void kernel_launch(void* const* d_in, const int* in_sizes, int n_in,
                              void* d_out, int out_size, void* d_ws, size_t ws_size,
                              hipStream_t stream) {
    const float* query   = (const float*)d_in[0];
    const float* context = (const float*)d_in[1];
    const float* Wq      = (const float*)d_in[2];
    const float* bq      = (const float*)d_in[3];
    const float* Wc      = (const float*)d_in[4];
    const float* bc      = (const float*)d_in[5];
    float* out = (float*)d_out;

    unsigned short* wfrag = (unsigned short*)d_ws;            // 1 MB
    const size_t actElems = (size_t)NB * SEQ * DIM;           // 33.5M
    unsigned short* actQ  = wfrag + 524288;                   // +1 MB, 64 MB
    unsigned short* actC  = actQ + actElems;                  // +65 MB, 64 MB
    const size_t need = (524288 + 2 * actElems) * sizeof(unsigned short);

    prep_weights<<<256, 256, 0, stream>>>(Wq, Wc, wfrag);
    if (ws_size >= need) {
        const int pblocks = (int)(actElems / (8 * 256));      // 16384
        prep_acts<<<pblocks, 256, 0, stream>>>(query, actQ);
        prep_acts<<<pblocks, 256, 0, stream>>>(context, actC);
        coattn<true><<<NB * 2, 256, 0, stream>>>(query, context, actQ, actC,
                                                 bq, bc, wfrag, out);
    } else {
        coattn<false><<<NB * 2, 256, 0, stream>>>(query, context, actQ, actC,
                                                  bq, bc, wfrag, out);
    }
}

// Round 5
// 430.535 us; speedup vs baseline: 1.1237x; 1.1237x over previous
//
#include <hip/hip_runtime.h>
#include <hip/hip_bf16.h>

typedef float  f32x4 __attribute__((ext_vector_type(4)));
typedef short  s16x8 __attribute__((ext_vector_type(8)));

#define NB   1024
#define SEQ  64
#define DIM  512
#define NH   8
#define SCALE 0.044194173824159216f

// round-half-up f32->bf16: 2 VALU ops
static __device__ __forceinline__ unsigned short f2bf(float f) {
    unsigned u = __builtin_bit_cast(unsigned, f);
    return (unsigned short)((u + 0x8000u) >> 16);
}

static __device__ __forceinline__ f32x4 mma(s16x8 a, s16x8 b, f32x4 c) {
    return __builtin_amdgcn_mfma_f32_16x16x32_bf16(a, b, c, 0, 0, 0);
}

// load 8 consecutive f32, convert to a bf16 frag slice
static __device__ __forceinline__ s16x8 ldcvt(const float* p) {
    float4 v0 = *(const float4*)(p);
    float4 v1 = *(const float4*)(p + 4);
    s16x8 r;
    r[0] = (short)f2bf(v0.x); r[1] = (short)f2bf(v0.y);
    r[2] = (short)f2bf(v0.z); r[3] = (short)f2bf(v0.w);
    r[4] = (short)f2bf(v1.x); r[5] = (short)f2bf(v1.y);
    r[6] = (short)f2bf(v1.z); r[7] = (short)f2bf(v1.w);
    return r;
}

// Pre-kernel: convert Wq, Wc (f32 [512][512] row-major, [k][n]) into bf16
// B-fragment order: m in {0,1}, tile 0..31, ks 0..15, lane 0..63:
// 8 bf16 = W[ks*32 + (lane>>4)*8 + j][tile*16 + (lane&15)].
__global__ __launch_bounds__(256) void prep_weights(
    const float* __restrict__ Wq, const float* __restrict__ Wc,
    unsigned short* __restrict__ wf)
{
    int gid  = blockIdx.x * 256 + threadIdx.x;   // 0..65535
    int m    = gid >> 15;
    int tile = (gid >> 10) & 31;
    int ks   = (gid >> 6) & 15;
    int lane = gid & 63;
    const float* W = m ? Wc : Wq;
    int col = tile * 16 + (lane & 15);
    int k0  = ks * 32 + (lane >> 4) * 8;
    unsigned short* dst = wf + (size_t)gid * 8;
#pragma unroll
    for (int j = 0; j < 8; ++j)
        dst[j] = f2bf(W[(size_t)(k0 + j) * DIM + col]);
}

// ====================== Kernel 1: projections ======================
// One wave -> one (b, m, h) 64x64 bf16 output tile (bias folded in).
// Low regs (~acc 64 + frags 32) -> 3-4 waves/SIMD; no LDS; streaming.
// pp layout: [m][b][h][64][64] bf16.
__global__ __launch_bounds__(256) void proj_kernel(
    const float* __restrict__ query,
    const float* __restrict__ context,
    const float* __restrict__ bq,
    const float* __restrict__ bc,
    const unsigned short* __restrict__ wf,
    unsigned short* __restrict__ pp)
{
    const int lane = threadIdx.x & 63;
    const int wv   = threadIdx.x >> 6;
    const int l15  = lane & 15;
    const int l4   = lane >> 4;

    // 4096 blocks; swizzle so orig-consecutive blocks (same b) share an XCD.
    const int i    = blockIdx.x;
    const int orig = (i & 7) * 512 + (i >> 3);
    const int b    = orig >> 2;
    const int m    = (orig >> 1) & 1;
    const int hq   = orig & 1;
    const int h    = hq * 4 + wv;

    const float* act  = (m ? context : query) + (size_t)b * SEQ * DIM;
    const float* bias = m ? bc : bq;
    const unsigned short* wfm = wf + (size_t)m * 262144;

    const f32x4 fz = {0.f, 0.f, 0.f, 0.f};
    f32x4 acc[4][4];
#pragma unroll
    for (int x = 0; x < 4; ++x)
#pragma unroll
        for (int y = 0; y < 4; ++y) acc[x][y] = fz;

    for (int ks = 0; ks < 16; ++ks) {
        const int k0 = ks * 32 + l4 * 8;
        s16x8 af[4], bf[4];
#pragma unroll
        for (int mt = 0; mt < 4; ++mt)
            af[mt] = ldcvt(act + (size_t)(mt * 16 + l15) * DIM + k0);
#pragma unroll
        for (int nt = 0; nt < 4; ++nt)
            bf[nt] = *(const s16x8*)(wfm +
                     ((size_t)((h * 4 + nt) * 16 + ks) * 64 + lane) * 8);
#pragma unroll
        for (int mt = 0; mt < 4; ++mt)
#pragma unroll
            for (int nt = 0; nt < 4; ++nt)
                acc[mt][nt] = mma(af[mt], bf[nt], acc[mt][nt]);
    }

    unsigned short* dst = pp + (((size_t)m * NB + b) * NH + h) * 4096;
#pragma unroll
    for (int nt = 0; nt < 4; ++nt) {
        float bv = bias[h * 64 + nt * 16 + l15];
#pragma unroll
        for (int mt = 0; mt < 4; ++mt)
#pragma unroll
            for (int r = 0; r < 4; ++r)
                dst[(mt * 16 + l4 * 4 + r) * 64 + nt * 16 + l15] =
                    f2bf(acc[mt][nt][r] + bv);
    }
}

// ====================== Kernel 2: attention tail ======================
// One wave -> one (b,h). cb/qa as direct global frag loads; Qp staged in
// per-wave LDS only for the qb transpose; P1/P2^T reuse the same tile.
__global__ __launch_bounds__(256) void tail_kernel(
    const unsigned short* __restrict__ pp,
    float* __restrict__ out)
{
    __shared__ unsigned short sT[4][SEQ][72];

    const int lane = threadIdx.x & 63;
    const int wv   = threadIdx.x >> 6;
    const int l15  = lane & 15;
    const int l4   = lane >> 4;

    // 2048 blocks; same-b blocks adjacent on an XCD.
    const int i    = blockIdx.x;
    const int orig = (i & 7) * 256 + (i >> 3);
    const int b    = orig >> 1;
    const int half = orig & 1;
    const int h    = half * 4 + wv;

    const unsigned short* qp = pp + ((size_t)b * NH + h) * 4096;
    const unsigned short* cp = pp + (((size_t)NB + b) * NH + h) * 4096;

    const f32x4 fz = {0.f, 0.f, 0.f, 0.f};
    unsigned short (*T)[72] = sT[wv];

    // Cp^T B-frags and Qp A-frags: direct global loads (16B/lane)
    s16x8 cb[4][2], qa[4][2];
#pragma unroll
    for (int nt = 0; nt < 4; ++nt)
#pragma unroll
        for (int ks = 0; ks < 2; ++ks)
            cb[nt][ks] = *(const s16x8*)(cp + (nt * 16 + l15) * 64 + ks * 32 + l4 * 8);
#pragma unroll
    for (int mt = 0; mt < 4; ++mt)
#pragma unroll
        for (int ks = 0; ks < 2; ++ks)
            qa[mt][ks] = *(const s16x8*)(qp + (mt * 16 + l15) * 64 + ks * 32 + l4 * 8);

    // stage Qp into LDS (coalesced 1KB per instr) for the transpose read
#pragma unroll
    for (int j = 0; j < 8; ++j) {
        int row = j * 8 + (lane >> 3);
        int col = (lane & 7) * 8;
        *(s16x8*)&T[row][col] = *(const s16x8*)(qp + row * 64 + col);
    }

    // qb = Qp^T B-frags (scalar transpose reads from LDS)
    s16x8 qb[4][2];
#pragma unroll
    for (int nt = 0; nt < 4; ++nt)
#pragma unroll
        for (int ks = 0; ks < 2; ++ks) {
            s16x8 v;
#pragma unroll
            for (int j = 0; j < 8; ++j)
                v[j] = (short)T[ks * 32 + l4 * 8 + j][nt * 16 + l15];
            qb[nt][ks] = v;
        }

    // ===== attn logits Sc = Qp @ Cp^T =====
    f32x4 Sc[4][4];
#pragma unroll
    for (int x = 0; x < 4; ++x)
#pragma unroll
        for (int y = 0; y < 4; ++y) Sc[x][y] = fz;
#pragma unroll
    for (int ks = 0; ks < 2; ++ks)
#pragma unroll
        for (int mt = 0; mt < 4; ++mt)
#pragma unroll
            for (int nt = 0; nt < 4; ++nt)
                Sc[mt][nt] = mma(qa[mt][ks], cb[nt][ks], Sc[mt][nt]);

    // ===== softmax over keys (rows): P1 -> T =====
#pragma unroll
    for (int mt = 0; mt < 4; ++mt)
#pragma unroll
        for (int r = 0; r < 4; ++r) {
            float m = fmaxf(fmaxf(Sc[mt][0][r], Sc[mt][1][r]),
                            fmaxf(Sc[mt][2][r], Sc[mt][3][r]));
            m = fmaxf(m, __shfl_xor(m, 1));
            m = fmaxf(m, __shfl_xor(m, 2));
            m = fmaxf(m, __shfl_xor(m, 4));
            m = fmaxf(m, __shfl_xor(m, 8));
            float e[4], s = 0.f;
#pragma unroll
            for (int nt = 0; nt < 4; ++nt) { e[nt] = __expf(SCALE * (Sc[mt][nt][r] - m)); s += e[nt]; }
            s += __shfl_xor(s, 1);
            s += __shfl_xor(s, 2);
            s += __shfl_xor(s, 4);
            s += __shfl_xor(s, 8);
            float inv = 1.f / s;
            int row = mt * 16 + l4 * 4 + r;
#pragma unroll
            for (int nt = 0; nt < 4; ++nt)
                T[row][nt * 16 + l15] = f2bf(e[nt] * inv);
        }

    s16x8 pa[4][2];
#pragma unroll
    for (int mt = 0; mt < 4; ++mt)
#pragma unroll
        for (int ks = 0; ks < 2; ++ks)
            pa[mt][ks] = *(const s16x8*)&T[mt * 16 + l15][ks * 32 + l4 * 8];

    // ===== softmax over queries (cols): P2^T -> T (releases Sc) =====
#pragma unroll
    for (int nt = 0; nt < 4; ++nt) {
        float m = -1e30f;
#pragma unroll
        for (int mt = 0; mt < 4; ++mt)
#pragma unroll
            for (int r = 0; r < 4; ++r) m = fmaxf(m, Sc[mt][nt][r]);
        m = fmaxf(m, __shfl_xor(m, 16));
        m = fmaxf(m, __shfl_xor(m, 32));
        float ee[4][4], s = 0.f;
#pragma unroll
        for (int mt = 0; mt < 4; ++mt)
#pragma unroll
            for (int r = 0; r < 4; ++r) { ee[mt][r] = __expf(SCALE * (Sc[mt][nt][r] - m)); s += ee[mt][r]; }
        s += __shfl_xor(s, 16);
        s += __shfl_xor(s, 32);
        float inv = 1.f / s;
        int krow = nt * 16 + l15;
#pragma unroll
        for (int mt = 0; mt < 4; ++mt)
#pragma unroll
            for (int r = 0; r < 4; ++r)
                T[krow][mt * 16 + l4 * 4 + r] = f2bf(ee[mt][r] * inv);
    }

    // ===== c_coattn = P1 @ Cp^T ; store =====
    f32x4 O[4][4];
#pragma unroll
    for (int x = 0; x < 4; ++x)
#pragma unroll
        for (int y = 0; y < 4; ++y) O[x][y] = fz;
#pragma unroll
    for (int ks = 0; ks < 2; ++ks)
#pragma unroll
        for (int mt = 0; mt < 4; ++mt)
#pragma unroll
            for (int nt = 0; nt < 4; ++nt)
                O[mt][nt] = mma(pa[mt][ks], cb[nt][ks], O[mt][nt]);

    float* cO = out;
#pragma unroll
    for (int mt = 0; mt < 4; ++mt)
#pragma unroll
        for (int nt = 0; nt < 4; ++nt)
#pragma unroll
            for (int r = 0; r < 4; ++r) {
                int qrow = mt * 16 + l4 * 4 + r;
                cO[((size_t)b * SEQ + qrow) * (NH * 64) + h * 64 + nt * 16 + l15] = O[mt][nt][r];
            }

    // ===== q_coattn = P2^T @ Qp ; store =====
    s16x8 p2a[4][2];
#pragma unroll
    for (int mt = 0; mt < 4; ++mt)
#pragma unroll
        for (int ks = 0; ks < 2; ++ks)
            p2a[mt][ks] = *(const s16x8*)&T[mt * 16 + l15][ks * 32 + l4 * 8];

#pragma unroll
    for (int x = 0; x < 4; ++x)
#pragma unroll
        for (int y = 0; y < 4; ++y) O[x][y] = fz;
#pragma unroll
    for (int ks = 0; ks < 2; ++ks)
#pragma unroll
        for (int mt = 0; mt < 4; ++mt)
#pragma unroll
            for (int nt = 0; nt < 4; ++nt)
                O[mt][nt] = mma(p2a[mt][ks], qb[nt][ks], O[mt][nt]);

    float* qO = out + (size_t)NB * SEQ * NH * 64;
#pragma unroll
    for (int mt = 0; mt < 4; ++mt)
#pragma unroll
        for (int nt = 0; nt < 4; ++nt)
#pragma unroll
            for (int r = 0; r < 4; ++r) {
                int krow = mt * 16 + l4 * 4 + r;
                qO[((size_t)b * SEQ + krow) * (NH * 64) + h * 64 + nt * 16 + l15] = O[mt][nt][r];
            }
}

// ====================== Fallback: fused (round-3 style) ======================
__global__ __launch_bounds__(256) void coattn_fused(
    const float* __restrict__ query,
    const float* __restrict__ context,
    const float* __restrict__ bq,
    const float* __restrict__ bc,
    const unsigned short* __restrict__ wf,
    float* __restrict__ out)
{
    __shared__ unsigned short sT[4][SEQ][72];
    const int tid  = threadIdx.x;
    const int lane = tid & 63;
    const int wv   = tid >> 6;
    const int l15  = lane & 15;
    const int l4   = lane >> 4;
    const int B_id = blockIdx.x;
    const int half = (B_id >> 3) & 1;
    const int b    = (B_id & 7) | ((B_id >> 4) << 3);
    const int h    = half * 4 + wv;
    const float* gq = query   + (size_t)b * SEQ * DIM;
    const float* gc = context + (size_t)b * SEQ * DIM;
    const f32x4 fz = {0.f, 0.f, 0.f, 0.f};
    unsigned short (*T)[72] = sT[wv];
    f32x4 acc[4][4];
#pragma unroll
    for (int i = 0; i < 4; ++i)
#pragma unroll
        for (int j = 0; j < 4; ++j) acc[i][j] = fz;
    for (int ks = 0; ks < 16; ++ks) {
        const int k0 = ks * 32 + l4 * 8;
        s16x8 af[4], bf[4];
#pragma unroll
        for (int mt = 0; mt < 4; ++mt)
            af[mt] = ldcvt(gc + (size_t)(mt * 16 + l15) * DIM + k0);
#pragma unroll
        for (int nt = 0; nt < 4; ++nt)
            bf[nt] = *(const s16x8*)(wf + 262144 +
                     ((size_t)((h * 4 + nt) * 16 + ks) * 64 + lane) * 8);
#pragma unroll
        for (int mt = 0; mt < 4; ++mt)
#pragma unroll
            for (int nt = 0; nt < 4; ++nt)
                acc[mt][nt] = mma(af[mt], bf[nt], acc[mt][nt]);
    }
#pragma unroll
    for (int nt = 0; nt < 4; ++nt) {
        float bcv = bc[h * 64 + nt * 16 + l15];
#pragma unroll
        for (int mt = 0; mt < 4; ++mt)
#pragma unroll
            for (int r = 0; r < 4; ++r)
                T[mt * 16 + l4 * 4 + r][nt * 16 + l15] = f2bf(acc[mt][nt][r] + bcv);
    }
    s16x8 cb[4][2];
#pragma unroll
    for (int nt = 0; nt < 4; ++nt)
#pragma unroll
        for (int ks = 0; ks < 2; ++ks)
            cb[nt][ks] = *(const s16x8*)&T[nt * 16 + l15][ks * 32 + l4 * 8];
#pragma unroll
    for (int i = 0; i < 4; ++i)
#pragma unroll
        for (int j = 0; j < 4; ++j) acc[i][j] = fz;
    for (int ks = 0; ks < 16; ++ks) {
        const int k0 = ks * 32 + l4 * 8;
        s16x8 af[4], bf[4];
#pragma unroll
        for (int mt = 0; mt < 4; ++mt)
            af[mt] = ldcvt(gq + (size_t)(mt * 16 + l15) * DIM + k0);
#pragma unroll
        for (int nt = 0; nt < 4; ++nt)
            bf[nt] = *(const s16x8*)(wf +
                     ((size_t)((h * 4 + nt) * 16 + ks) * 64 + lane) * 8);
#pragma unroll
        for (int mt = 0; mt < 4; ++mt)
#pragma unroll
            for (int nt = 0; nt < 4; ++nt)
                acc[mt][nt] = mma(af[mt], bf[nt], acc[mt][nt]);
    }
#pragma unroll
    for (int nt = 0; nt < 4; ++nt) {
        float bqv = bq[h * 64 + nt * 16 + l15];
#pragma unroll
        for (int mt = 0; mt < 4; ++mt)
#pragma unroll
            for (int r = 0; r < 4; ++r)
                T[mt * 16 + l4 * 4 + r][nt * 16 + l15] = f2bf(acc[mt][nt][r] + bqv);
    }
    s16x8 qa[4][2], qb[4][2];
#pragma unroll
    for (int mt = 0; mt < 4; ++mt)
#pragma unroll
        for (int ks = 0; ks < 2; ++ks)
            qa[mt][ks] = *(const s16x8*)&T[mt * 16 + l15][ks * 32 + l4 * 8];
#pragma unroll
    for (int nt = 0; nt < 4; ++nt)
#pragma unroll
        for (int ks = 0; ks < 2; ++ks) {
            s16x8 v;
#pragma unroll
            for (int j = 0; j < 8; ++j)
                v[j] = (short)T[ks * 32 + l4 * 8 + j][nt * 16 + l15];
            qb[nt][ks] = v;
        }
    f32x4 Sc[4][4];
#pragma unroll
    for (int i = 0; i < 4; ++i)
#pragma unroll
        for (int j = 0; j < 4; ++j) Sc[i][j] = fz;
#pragma unroll
    for (int ks = 0; ks < 2; ++ks)
#pragma unroll
        for (int mt = 0; mt < 4; ++mt)
#pragma unroll
            for (int nt = 0; nt < 4; ++nt)
                Sc[mt][nt] = mma(qa[mt][ks], cb[nt][ks], Sc[mt][nt]);
#pragma unroll
    for (int mt = 0; mt < 4; ++mt)
#pragma unroll
        for (int r = 0; r < 4; ++r) {
            float m = fmaxf(fmaxf(Sc[mt][0][r], Sc[mt][1][r]),
                            fmaxf(Sc[mt][2][r], Sc[mt][3][r]));
            m = fmaxf(m, __shfl_xor(m, 1));
            m = fmaxf(m, __shfl_xor(m, 2));
            m = fmaxf(m, __shfl_xor(m, 4));
            m = fmaxf(m, __shfl_xor(m, 8));
            float e[4], s = 0.f;
#pragma unroll
            for (int nt = 0; nt < 4; ++nt) { e[nt] = __expf(SCALE * (Sc[mt][nt][r] - m)); s += e[nt]; }
            s += __shfl_xor(s, 1);
            s += __shfl_xor(s, 2);
            s += __shfl_xor(s, 4);
            s += __shfl_xor(s, 8);
            float inv = 1.f / s;
            int row = mt * 16 + l4 * 4 + r;
#pragma unroll
            for (int nt = 0; nt < 4; ++nt)
                T[row][nt * 16 + l15] = f2bf(e[nt] * inv);
        }
    s16x8 pa[4][2];
#pragma unroll
    for (int mt = 0; mt < 4; ++mt)
#pragma unroll
        for (int ks = 0; ks < 2; ++ks)
            pa[mt][ks] = *(const s16x8*)&T[mt * 16 + l15][ks * 32 + l4 * 8];
#pragma unroll
    for (int nt = 0; nt < 4; ++nt) {
        float m = -1e30f;
#pragma unroll
        for (int mt = 0; mt < 4; ++mt)
#pragma unroll
            for (int r = 0; r < 4; ++r) m = fmaxf(m, Sc[mt][nt][r]);
        m = fmaxf(m, __shfl_xor(m, 16));
        m = fmaxf(m, __shfl_xor(m, 32));
        float ee[4][4], s = 0.f;
#pragma unroll
        for (int mt = 0; mt < 4; ++mt)
#pragma unroll
            for (int r = 0; r < 4; ++r) { ee[mt][r] = __expf(SCALE * (Sc[mt][nt][r] - m)); s += ee[mt][r]; }
        s += __shfl_xor(s, 16);
        s += __shfl_xor(s, 32);
        float inv = 1.f / s;
        int krow = nt * 16 + l15;
#pragma unroll
        for (int mt = 0; mt < 4; ++mt)
#pragma unroll
            for (int r = 0; r < 4; ++r)
                T[krow][mt * 16 + l4 * 4 + r] = f2bf(ee[mt][r] * inv);
    }
    s16x8 p2a[4][2];
#pragma unroll
    for (int mt = 0; mt < 4; ++mt)
#pragma unroll
        for (int ks = 0; ks < 2; ++ks)
            p2a[mt][ks] = *(const s16x8*)&T[mt * 16 + l15][ks * 32 + l4 * 8];
    f32x4 O[4][4];
#pragma unroll
    for (int i = 0; i < 4; ++i)
#pragma unroll
        for (int j = 0; j < 4; ++j) O[i][j] = fz;
#pragma unroll
    for (int ks = 0; ks < 2; ++ks)
#pragma unroll
        for (int mt = 0; mt < 4; ++mt)
#pragma unroll
            for (int nt = 0; nt < 4; ++nt)
                O[mt][nt] = mma(pa[mt][ks], cb[nt][ks], O[mt][nt]);
    float* cO = out;
#pragma unroll
    for (int mt = 0; mt < 4; ++mt)
#pragma unroll
        for (int nt = 0; nt < 4; ++nt)
#pragma unroll
            for (int r = 0; r < 4; ++r) {
                int qrow = mt * 16 + l4 * 4 + r;
                cO[((size_t)b * SEQ + qrow) * (NH * 64) + h * 64 + nt * 16 + l15] = O[mt][nt][r];
            }
#pragma unroll
    for (int i = 0; i < 4; ++i)
#pragma unroll
        for (int j = 0; j < 4; ++j) O[i][j] = fz;
#pragma unroll
    for (int ks = 0; ks < 2; ++ks)
#pragma unroll
        for (int mt = 0; mt < 4; ++mt)
#pragma unroll
            for (int nt = 0; nt < 4; ++nt)
                O[mt][nt] = mma(p2a[mt][ks], qb[nt][ks], O[mt][nt]);
    float* qO = out + (size_t)NB * SEQ * NH * 64;
#pragma unroll
    for (int mt = 0; mt < 4; ++mt)
#pragma unroll
        for (int nt = 0; nt < 4; ++nt)
#pragma unroll
            for (int r = 0; r < 4; ++r) {
                int krow = mt * 16 + l4 * 4 + r;
                qO[((size_t)b * SEQ + krow) * (NH * 64) + h * 64 + nt * 16 + l15] = O[mt][nt][r];
            }
}

extern "C" void kernel_launch(void* const* d_in, const int* in_sizes, int n_in,
                              void* d_out, int out_size, void* d_ws, size_t ws_size,
                              hipStream_t stream) {
    const float* query   = (const float*)d_in[0];
    const float* context = (const float*)d_in[1];
    const float* Wq      = (const float*)d_in[2];
    const float* bq      = (const float*)d_in[3];
    const float* Wc      = (const float*)d_in[4];
    const float* bc      = (const float*)d_in[5];
    float* out = (float*)d_out;

    unsigned short* wfrag = (unsigned short*)d_ws;            // 1 MB
    unsigned short* pp    = wfrag + 524288;                   // 134.2 MB
    const size_t need = (524288 + (size_t)2 * NB * NH * 4096) * sizeof(unsigned short);

    prep_weights<<<256, 256, 0, stream>>>(Wq, Wc, wfrag);
    if (ws_size >= need) {
        proj_kernel<<<4096, 256, 0, stream>>>(query, context, bq, bc, wfrag, pp);
        tail_kernel<<<2048, 256, 0, stream>>>(pp, out);
    } else {
        coattn_fused<<<NB * 2, 256, 0, stream>>>(query, context, bq, bc, wfrag, out);
    }
}

// Round 6
// 272.358 us; speedup vs baseline: 1.7763x; 1.5808x over previous
//
#include <hip/hip_runtime.h>
#include <hip/hip_bf16.h>

typedef float  f32x4 __attribute__((ext_vector_type(4)));
typedef short  s16x8 __attribute__((ext_vector_type(8)));

#define NB   1024
#define SEQ  64
#define DIM  512
#define NH   8
#define SCALE 0.044194173824159216f

// round-half-up f32->bf16: 2 VALU ops
static __device__ __forceinline__ unsigned short f2bf(float f) {
    unsigned u = __builtin_bit_cast(unsigned, f);
    return (unsigned short)((u + 0x8000u) >> 16);
}

static __device__ __forceinline__ f32x4 mma(s16x8 a, s16x8 b, f32x4 c) {
    return __builtin_amdgcn_mfma_f32_16x16x32_bf16(a, b, c, 0, 0, 0);
}

// load 8 consecutive f32, convert to a bf16 frag slice (fallback path)
static __device__ __forceinline__ s16x8 ldcvt(const float* p) {
    float4 v0 = *(const float4*)(p);
    float4 v1 = *(const float4*)(p + 4);
    s16x8 r;
    r[0] = (short)f2bf(v0.x); r[1] = (short)f2bf(v0.y);
    r[2] = (short)f2bf(v0.z); r[3] = (short)f2bf(v0.w);
    r[4] = (short)f2bf(v1.x); r[5] = (short)f2bf(v1.y);
    r[6] = (short)f2bf(v1.z); r[7] = (short)f2bf(v1.w);
    return r;
}

// Pre-kernel: Wq, Wc (f32 [512][512] row-major [k][n]) -> bf16 B-fragment order.
__global__ __launch_bounds__(256) void prep_weights(
    const float* __restrict__ Wq, const float* __restrict__ Wc,
    unsigned short* __restrict__ wf)
{
    int gid  = blockIdx.x * 256 + threadIdx.x;   // 0..65535
    int m    = gid >> 15;
    int tile = (gid >> 10) & 31;
    int ks   = (gid >> 6) & 15;
    int lane = gid & 63;
    const float* W = m ? Wc : Wq;
    int col = tile * 16 + (lane & 15);
    int k0  = ks * 32 + (lane >> 4) * 8;
    unsigned short* dst = wf + (size_t)gid * 8;
#pragma unroll
    for (int j = 0; j < 8; ++j)
        dst[j] = f2bf(W[(size_t)(k0 + j) * DIM + col]);
}

// ====================== Kernel 1: projections ======================
// One 512-thread block = one (b, m); 8 waves = 8 heads.
// Phase 1: bulk-stage 64x512 f32 act tile -> bf16 LDS in FRAGMENT-MAJOR order
//   elem (row, c) at ((c>>5)*64 + row)*4 + ((c>>3)&3), in 8-elem chunks
//   -> phase-2 A-frag ds_read_b128 = 64 consecutive 16B slots (conflict-free).
// Phase 2: per-wave 16 K-steps of {4 ds_read_b128 + 4 L2-hot weight loads
//   + 16 MFMA}; no global latency in the dependence chain.
__global__ __launch_bounds__(512) void proj_kernel(
    const float* __restrict__ query,
    const float* __restrict__ context,
    const float* __restrict__ bq,
    const float* __restrict__ bc,
    const unsigned short* __restrict__ wf,
    unsigned short* __restrict__ pp)
{
    __shared__ unsigned short sA[SEQ * DIM];   // 64 KB, fragment-major

    const int tid  = threadIdx.x;
    const int lane = tid & 63;
    const int wv   = tid >> 6;        // wave id = head
    const int l15  = lane & 15;
    const int l4   = lane >> 4;

    // chunked swizzle: grid 2048; consecutive orig ids (the two m's of one b,
    // then next b) land on the same XCD for act/L2 locality.
    const int i    = blockIdx.x;
    const int orig = (i & 7) * 256 + (i >> 3);
    const int b    = orig >> 1;
    const int m    = orig & 1;
    const int h    = wv;

    const float* act  = (m ? context : query) + (size_t)b * SEQ * DIM;
    const float* bias = m ? bc : bq;
    const unsigned short* wfm = wf + (size_t)m * 262144;

    // ---------- Phase 1: stage tile (coalesced reads, frag-major writes) ----
    // iter j: rows j*8 .. j*8+7 ; thread covers row j*8 + (tid>>6), cols (tid&63)*8..+7
    {
        const int r  = (tid >> 6);            // 0..7 within iter
        const int c0 = (tid & 63) * 8;
        const int ks = c0 >> 5;
        const int q4 = (c0 >> 3) & 3;
#pragma unroll
        for (int j = 0; j < 8; ++j) {
            const int row = j * 8 + r;
            const float* src = act + (size_t)row * DIM + c0;
            float4 v0 = *(const float4*)(src);
            float4 v1 = *(const float4*)(src + 4);
            s16x8 x;
            x[0] = (short)f2bf(v0.x); x[1] = (short)f2bf(v0.y);
            x[2] = (short)f2bf(v0.z); x[3] = (short)f2bf(v0.w);
            x[4] = (short)f2bf(v1.x); x[5] = (short)f2bf(v1.y);
            x[6] = (short)f2bf(v1.z); x[7] = (short)f2bf(v1.w);
            *(s16x8*)&sA[(((ks * 64 + row) * 4) + q4) * 8] = x;
        }
    }
    __syncthreads();

    // ---------- Phase 2: per-wave GEMM for head h ----------
    const f32x4 fz = {0.f, 0.f, 0.f, 0.f};
    f32x4 acc[4][4];
#pragma unroll
    for (int x = 0; x < 4; ++x)
#pragma unroll
        for (int y = 0; y < 4; ++y) acc[x][y] = fz;

    for (int ks = 0; ks < 16; ++ks) {
        s16x8 af[4], bf[4];
#pragma unroll
        for (int mt = 0; mt < 4; ++mt)
            af[mt] = *(const s16x8*)&sA[((ks * 64 + mt * 16 + l15) * 4 + l4) * 8];
#pragma unroll
        for (int nt = 0; nt < 4; ++nt)
            bf[nt] = *(const s16x8*)(wfm +
                     ((size_t)((h * 4 + nt) * 16 + ks) * 64 + lane) * 8);
#pragma unroll
        for (int mt = 0; mt < 4; ++mt)
#pragma unroll
            for (int nt = 0; nt < 4; ++nt)
                acc[mt][nt] = mma(af[mt], bf[nt], acc[mt][nt]);
    }

    unsigned short* dst = pp + (((size_t)m * NB + b) * NH + h) * 4096;
#pragma unroll
    for (int nt = 0; nt < 4; ++nt) {
        float bv = bias[h * 64 + nt * 16 + l15];
#pragma unroll
        for (int mt = 0; mt < 4; ++mt)
#pragma unroll
            for (int r = 0; r < 4; ++r)
                dst[(mt * 16 + l4 * 4 + r) * 64 + nt * 16 + l15] =
                    f2bf(acc[mt][nt][r] + bv);
    }
}

// ====================== Kernel 2: attention tail ======================
// One wave -> one (b,h). cb/qa as direct global frag loads; Qp staged in
// per-wave LDS only for the qb transpose; P1/P2^T reuse the same tile.
__global__ __launch_bounds__(256) void tail_kernel(
    const unsigned short* __restrict__ pp,
    float* __restrict__ out)
{
    __shared__ unsigned short sT[4][SEQ][72];

    const int lane = threadIdx.x & 63;
    const int wv   = threadIdx.x >> 6;
    const int l15  = lane & 15;
    const int l4   = lane >> 4;

    const int i    = blockIdx.x;
    const int orig = (i & 7) * 256 + (i >> 3);
    const int b    = orig >> 1;
    const int half = orig & 1;
    const int h    = half * 4 + wv;

    const unsigned short* qp = pp + ((size_t)b * NH + h) * 4096;
    const unsigned short* cp = pp + (((size_t)NB + b) * NH + h) * 4096;

    const f32x4 fz = {0.f, 0.f, 0.f, 0.f};
    unsigned short (*T)[72] = sT[wv];

    s16x8 cb[4][2], qa[4][2];
#pragma unroll
    for (int nt = 0; nt < 4; ++nt)
#pragma unroll
        for (int ks = 0; ks < 2; ++ks)
            cb[nt][ks] = *(const s16x8*)(cp + (nt * 16 + l15) * 64 + ks * 32 + l4 * 8);
#pragma unroll
    for (int mt = 0; mt < 4; ++mt)
#pragma unroll
        for (int ks = 0; ks < 2; ++ks)
            qa[mt][ks] = *(const s16x8*)(qp + (mt * 16 + l15) * 64 + ks * 32 + l4 * 8);

#pragma unroll
    for (int j = 0; j < 8; ++j) {
        int row = j * 8 + (lane >> 3);
        int col = (lane & 7) * 8;
        *(s16x8*)&T[row][col] = *(const s16x8*)(qp + row * 64 + col);
    }

    s16x8 qb[4][2];
#pragma unroll
    for (int nt = 0; nt < 4; ++nt)
#pragma unroll
        for (int ks = 0; ks < 2; ++ks) {
            s16x8 v;
#pragma unroll
            for (int j = 0; j < 8; ++j)
                v[j] = (short)T[ks * 32 + l4 * 8 + j][nt * 16 + l15];
            qb[nt][ks] = v;
        }

    f32x4 Sc[4][4];
#pragma unroll
    for (int x = 0; x < 4; ++x)
#pragma unroll
        for (int y = 0; y < 4; ++y) Sc[x][y] = fz;
#pragma unroll
    for (int ks = 0; ks < 2; ++ks)
#pragma unroll
        for (int mt = 0; mt < 4; ++mt)
#pragma unroll
            for (int nt = 0; nt < 4; ++nt)
                Sc[mt][nt] = mma(qa[mt][ks], cb[nt][ks], Sc[mt][nt]);

    // softmax over keys (rows): P1 -> T
#pragma unroll
    for (int mt = 0; mt < 4; ++mt)
#pragma unroll
        for (int r = 0; r < 4; ++r) {
            float m = fmaxf(fmaxf(Sc[mt][0][r], Sc[mt][1][r]),
                            fmaxf(Sc[mt][2][r], Sc[mt][3][r]));
            m = fmaxf(m, __shfl_xor(m, 1));
            m = fmaxf(m, __shfl_xor(m, 2));
            m = fmaxf(m, __shfl_xor(m, 4));
            m = fmaxf(m, __shfl_xor(m, 8));
            float e[4], s = 0.f;
#pragma unroll
            for (int nt = 0; nt < 4; ++nt) { e[nt] = __expf(SCALE * (Sc[mt][nt][r] - m)); s += e[nt]; }
            s += __shfl_xor(s, 1);
            s += __shfl_xor(s, 2);
            s += __shfl_xor(s, 4);
            s += __shfl_xor(s, 8);
            float inv = 1.f / s;
            int row = mt * 16 + l4 * 4 + r;
#pragma unroll
            for (int nt = 0; nt < 4; ++nt)
                T[row][nt * 16 + l15] = f2bf(e[nt] * inv);
        }

    s16x8 pa[4][2];
#pragma unroll
    for (int mt = 0; mt < 4; ++mt)
#pragma unroll
        for (int ks = 0; ks < 2; ++ks)
            pa[mt][ks] = *(const s16x8*)&T[mt * 16 + l15][ks * 32 + l4 * 8];

    // softmax over queries (cols): P2^T -> T
#pragma unroll
    for (int nt = 0; nt < 4; ++nt) {
        float m = -1e30f;
#pragma unroll
        for (int mt = 0; mt < 4; ++mt)
#pragma unroll
            for (int r = 0; r < 4; ++r) m = fmaxf(m, Sc[mt][nt][r]);
        m = fmaxf(m, __shfl_xor(m, 16));
        m = fmaxf(m, __shfl_xor(m, 32));
        float ee[4][4], s = 0.f;
#pragma unroll
        for (int mt = 0; mt < 4; ++mt)
#pragma unroll
            for (int r = 0; r < 4; ++r) { ee[mt][r] = __expf(SCALE * (Sc[mt][nt][r] - m)); s += ee[mt][r]; }
        s += __shfl_xor(s, 16);
        s += __shfl_xor(s, 32);
        float inv = 1.f / s;
        int krow = nt * 16 + l15;
#pragma unroll
        for (int mt = 0; mt < 4; ++mt)
#pragma unroll
            for (int r = 0; r < 4; ++r)
                T[krow][mt * 16 + l4 * 4 + r] = f2bf(ee[mt][r] * inv);
    }

    // c_coattn = P1 @ Cp^T
    f32x4 O[4][4];
#pragma unroll
    for (int x = 0; x < 4; ++x)
#pragma unroll
        for (int y = 0; y < 4; ++y) O[x][y] = fz;
#pragma unroll
    for (int ks = 0; ks < 2; ++ks)
#pragma unroll
        for (int mt = 0; mt < 4; ++mt)
#pragma unroll
            for (int nt = 0; nt < 4; ++nt)
                O[mt][nt] = mma(pa[mt][ks], cb[nt][ks], O[mt][nt]);

    float* cO = out;
#pragma unroll
    for (int mt = 0; mt < 4; ++mt)
#pragma unroll
        for (int nt = 0; nt < 4; ++nt)
#pragma unroll
            for (int r = 0; r < 4; ++r) {
                int qrow = mt * 16 + l4 * 4 + r;
                cO[((size_t)b * SEQ + qrow) * (NH * 64) + h * 64 + nt * 16 + l15] = O[mt][nt][r];
            }

    // q_coattn = P2^T @ Qp
    s16x8 p2a[4][2];
#pragma unroll
    for (int mt = 0; mt < 4; ++mt)
#pragma unroll
        for (int ks = 0; ks < 2; ++ks)
            p2a[mt][ks] = *(const s16x8*)&T[mt * 16 + l15][ks * 32 + l4 * 8];

#pragma unroll
    for (int x = 0; x < 4; ++x)
#pragma unroll
        for (int y = 0; y < 4; ++y) O[x][y] = fz;
#pragma unroll
    for (int ks = 0; ks < 2; ++ks)
#pragma unroll
        for (int mt = 0; mt < 4; ++mt)
#pragma unroll
            for (int nt = 0; nt < 4; ++nt)
                O[mt][nt] = mma(p2a[mt][ks], qb[nt][ks], O[mt][nt]);

    float* qO = out + (size_t)NB * SEQ * NH * 64;
#pragma unroll
    for (int mt = 0; mt < 4; ++mt)
#pragma unroll
        for (int nt = 0; nt < 4; ++nt)
#pragma unroll
            for (int r = 0; r < 4; ++r) {
                int krow = mt * 16 + l4 * 4 + r;
                qO[((size_t)b * SEQ + krow) * (NH * 64) + h * 64 + nt * 16 + l15] = O[mt][nt][r];
            }
}

// ====================== Fallback: fused (round-3 style) ======================
__global__ __launch_bounds__(256) void coattn_fused(
    const float* __restrict__ query,
    const float* __restrict__ context,
    const float* __restrict__ bq,
    const float* __restrict__ bc,
    const unsigned short* __restrict__ wf,
    float* __restrict__ out)
{
    __shared__ unsigned short sT[4][SEQ][72];
    const int tid  = threadIdx.x;
    const int lane = tid & 63;
    const int wv   = tid >> 6;
    const int l15  = lane & 15;
    const int l4   = lane >> 4;
    const int B_id = blockIdx.x;
    const int half = (B_id >> 3) & 1;
    const int b    = (B_id & 7) | ((B_id >> 4) << 3);
    const int h    = half * 4 + wv;
    const float* gq = query   + (size_t)b * SEQ * DIM;
    const float* gc = context + (size_t)b * SEQ * DIM;
    const f32x4 fz = {0.f, 0.f, 0.f, 0.f};
    unsigned short (*T)[72] = sT[wv];
    f32x4 acc[4][4];
#pragma unroll
    for (int i = 0; i < 4; ++i)
#pragma unroll
        for (int j = 0; j < 4; ++j) acc[i][j] = fz;
    for (int ks = 0; ks < 16; ++ks) {
        const int k0 = ks * 32 + l4 * 8;
        s16x8 af[4], bf[4];
#pragma unroll
        for (int mt = 0; mt < 4; ++mt)
            af[mt] = ldcvt(gc + (size_t)(mt * 16 + l15) * DIM + k0);
#pragma unroll
        for (int nt = 0; nt < 4; ++nt)
            bf[nt] = *(const s16x8*)(wf + 262144 +
                     ((size_t)((h * 4 + nt) * 16 + ks) * 64 + lane) * 8);
#pragma unroll
        for (int mt = 0; mt < 4; ++mt)
#pragma unroll
            for (int nt = 0; nt < 4; ++nt)
                acc[mt][nt] = mma(af[mt], bf[nt], acc[mt][nt]);
    }
#pragma unroll
    for (int nt = 0; nt < 4; ++nt) {
        float bcv = bc[h * 64 + nt * 16 + l15];
#pragma unroll
        for (int mt = 0; mt < 4; ++mt)
#pragma unroll
            for (int r = 0; r < 4; ++r)
                T[mt * 16 + l4 * 4 + r][nt * 16 + l15] = f2bf(acc[mt][nt][r] + bcv);
    }
    s16x8 cb[4][2];
#pragma unroll
    for (int nt = 0; nt < 4; ++nt)
#pragma unroll
        for (int ks = 0; ks < 2; ++ks)
            cb[nt][ks] = *(const s16x8*)&T[nt * 16 + l15][ks * 32 + l4 * 8];
#pragma unroll
    for (int i = 0; i < 4; ++i)
#pragma unroll
        for (int j = 0; j < 4; ++j) acc[i][j] = fz;
    for (int ks = 0; ks < 16; ++ks) {
        const int k0 = ks * 32 + l4 * 8;
        s16x8 af[4], bf[4];
#pragma unroll
        for (int mt = 0; mt < 4; ++mt)
            af[mt] = ldcvt(gq + (size_t)(mt * 16 + l15) * DIM + k0);
#pragma unroll
        for (int nt = 0; nt < 4; ++nt)
            bf[nt] = *(const s16x8*)(wf +
                     ((size_t)((h * 4 + nt) * 16 + ks) * 64 + lane) * 8);
#pragma unroll
        for (int mt = 0; mt < 4; ++mt)
#pragma unroll
            for (int nt = 0; nt < 4; ++nt)
                acc[mt][nt] = mma(af[mt], bf[nt], acc[mt][nt]);
    }
#pragma unroll
    for (int nt = 0; nt < 4; ++nt) {
        float bqv = bq[h * 64 + nt * 16 + l15];
#pragma unroll
        for (int mt = 0; mt < 4; ++mt)
#pragma unroll
            for (int r = 0; r < 4; ++r)
                T[mt * 16 + l4 * 4 + r][nt * 16 + l15] = f2bf(acc[mt][nt][r] + bqv);
    }
    s16x8 qa[4][2], qb[4][2];
#pragma unroll
    for (int mt = 0; mt < 4; ++mt)
#pragma unroll
        for (int ks = 0; ks < 2; ++ks)
            qa[mt][ks] = *(const s16x8*)&T[mt * 16 + l15][ks * 32 + l4 * 8];
#pragma unroll
    for (int nt = 0; nt < 4; ++nt)
#pragma unroll
        for (int ks = 0; ks < 2; ++ks) {
            s16x8 v;
#pragma unroll
            for (int j = 0; j < 8; ++j)
                v[j] = (short)T[ks * 32 + l4 * 8 + j][nt * 16 + l15];
            qb[nt][ks] = v;
        }
    f32x4 Sc[4][4];
#pragma unroll
    for (int i = 0; i < 4; ++i)
#pragma unroll
        for (int j = 0; j < 4; ++j) Sc[i][j] = fz;
#pragma unroll
    for (int ks = 0; ks < 2; ++ks)
#pragma unroll
        for (int mt = 0; mt < 4; ++mt)
#pragma unroll
            for (int nt = 0; nt < 4; ++nt)
                Sc[mt][nt] = mma(qa[mt][ks], cb[nt][ks], Sc[mt][nt]);
#pragma unroll
    for (int mt = 0; mt < 4; ++mt)
#pragma unroll
        for (int r = 0; r < 4; ++r) {
            float m = fmaxf(fmaxf(Sc[mt][0][r], Sc[mt][1][r]),
                            fmaxf(Sc[mt][2][r], Sc[mt][3][r]));
            m = fmaxf(m, __shfl_xor(m, 1));
            m = fmaxf(m, __shfl_xor(m, 2));
            m = fmaxf(m, __shfl_xor(m, 4));
            m = fmaxf(m, __shfl_xor(m, 8));
            float e[4], s = 0.f;
#pragma unroll
            for (int nt = 0; nt < 4; ++nt) { e[nt] = __expf(SCALE * (Sc[mt][nt][r] - m)); s += e[nt]; }
            s += __shfl_xor(s, 1);
            s += __shfl_xor(s, 2);
            s += __shfl_xor(s, 4);
            s += __shfl_xor(s, 8);
            float inv = 1.f / s;
            int row = mt * 16 + l4 * 4 + r;
#pragma unroll
            for (int nt = 0; nt < 4; ++nt)
                T[row][nt * 16 + l15] = f2bf(e[nt] * inv);
        }
    s16x8 pa[4][2];
#pragma unroll
    for (int mt = 0; mt < 4; ++mt)
#pragma unroll
        for (int ks = 0; ks < 2; ++ks)
            pa[mt][ks] = *(const s16x8*)&T[mt * 16 + l15][ks * 32 + l4 * 8];
#pragma unroll
    for (int nt = 0; nt < 4; ++nt) {
        float m = -1e30f;
#pragma unroll
        for (int mt = 0; mt < 4; ++mt)
#pragma unroll
            for (int r = 0; r < 4; ++r) m = fmaxf(m, Sc[mt][nt][r]);
        m = fmaxf(m, __shfl_xor(m, 16));
        m = fmaxf(m, __shfl_xor(m, 32));
        float ee[4][4], s = 0.f;
#pragma unroll
        for (int mt = 0; mt < 4; ++mt)
#pragma unroll
            for (int r = 0; r < 4; ++r) { ee[mt][r] = __expf(SCALE * (Sc[mt][nt][r] - m)); s += ee[mt][r]; }
        s += __shfl_xor(s, 16);
        s += __shfl_xor(s, 32);
        float inv = 1.f / s;
        int krow = nt * 16 + l15;
#pragma unroll
        for (int mt = 0; mt < 4; ++mt)
#pragma unroll
            for (int r = 0; r < 4; ++r)
                T[krow][mt * 16 + l4 * 4 + r] = f2bf(ee[mt][r] * inv);
    }
    s16x8 p2a[4][2];
#pragma unroll
    for (int mt = 0; mt < 4; ++mt)
#pragma unroll
        for (int ks = 0; ks < 2; ++ks)
            p2a[mt][ks] = *(const s16x8*)&T[mt * 16 + l15][ks * 32 + l4 * 8];
    f32x4 O[4][4];
#pragma unroll
    for (int i = 0; i < 4; ++i)
#pragma unroll
        for (int j = 0; j < 4; ++j) O[i][j] = fz;
#pragma unroll
    for (int ks = 0; ks < 2; ++ks)
#pragma unroll
        for (int mt = 0; mt < 4; ++mt)
#pragma unroll
            for (int nt = 0; nt < 4; ++nt)
                O[mt][nt] = mma(pa[mt][ks], cb[nt][ks], O[mt][nt]);
    float* cO = out;
#pragma unroll
    for (int mt = 0; mt < 4; ++mt)
#pragma unroll
        for (int nt = 0; nt < 4; ++nt)
#pragma unroll
            for (int r = 0; r < 4; ++r) {
                int qrow = mt * 16 + l4 * 4 + r;
                cO[((size_t)b * SEQ + qrow) * (NH * 64) + h * 64 + nt * 16 + l15] = O[mt][nt][r];
            }
#pragma unroll
    for (int i = 0; i < 4; ++i)
#pragma unroll
        for (int j = 0; j < 4; ++j) O[i][j] = fz;
#pragma unroll
    for (int ks = 0; ks < 2; ++ks)
#pragma unroll
        for (int mt = 0; mt < 4; ++mt)
#pragma unroll
            for (int nt = 0; nt < 4; ++nt)
                O[mt][nt] = mma(p2a[mt][ks], qb[nt][ks], O[mt][nt]);
    float* qO = out + (size_t)NB * SEQ * NH * 64;
#pragma unroll
    for (int mt = 0; mt < 4; ++mt)
#pragma unroll
        for (int nt = 0; nt < 4; ++nt)
#pragma unroll
            for (int r = 0; r < 4; ++r) {
                int krow = mt * 16 + l4 * 4 + r;
                qO[((size_t)b * SEQ + krow) * (NH * 64) + h * 64 + nt * 16 + l15] = O[mt][nt][r];
            }
}

extern "C" void kernel_launch(void* const* d_in, const int* in_sizes, int n_in,
                              void* d_out, int out_size, void* d_ws, size_t ws_size,
                              hipStream_t stream) {
    const float* query   = (const float*)d_in[0];
    const float* context = (const float*)d_in[1];
    const float* Wq      = (const float*)d_in[2];
    const float* bq      = (const float*)d_in[3];
    const float* Wc      = (const float*)d_in[4];
    const float* bc      = (const float*)d_in[5];
    float* out = (float*)d_out;

    unsigned short* wfrag = (unsigned short*)d_ws;            // 1 MB
    unsigned short* pp    = wfrag + 524288;                   // 134.2 MB
    const size_t need = (524288 + (size_t)2 * NB * NH * 4096) * sizeof(unsigned short);

    prep_weights<<<256, 256, 0, stream>>>(Wq, Wc, wfrag);
    if (ws_size >= need) {
        proj_kernel<<<2048, 512, 0, stream>>>(query, context, bq, bc, wfrag, pp);
        tail_kernel<<<2048, 256, 0, stream>>>(pp, out);
    } else {
        coattn_fused<<<NB * 2, 256, 0, stream>>>(query, context, bq, bc, wfrag, out);
    }
}